// Round 7
// baseline (16612.209 us; speedup 1.0000x reference)
//
#include <hip/hip_runtime.h>
#include <math.h>

#define TT 64
#define LV1 40   // V1 LDS k-stride (ushorts): 80B rows, 16B-aligned
#define LV2 72   // V2 LDS k-stride (ushorts): 144B rows, 16B-aligned

typedef float f32x4 __attribute__((ext_vector_type(4)));
typedef short s16x8 __attribute__((ext_vector_type(8)));
#define MFMA(a, b, c) __builtin_amdgcn_mfma_f32_16x16x32_bf16(a, b, c, 0, 0, 0)

__device__ __forceinline__ ushort rne_bf16(float x) {
    unsigned u = __builtin_bit_cast(unsigned, x);
    unsigned r = u + 0x7FFFu + ((u >> 16) & 1u);
    return (ushort)(r >> 16);
}
__device__ __forceinline__ float bf16_f32(ushort h) {
    unsigned u = ((unsigned)h) << 16;
    return __builtin_bit_cast(float, u);
}
__device__ __forceinline__ void split2(float x, ushort& hi, ushort& lo) {
    ushort h = rne_bf16(x);
    hi = h;
    lo = rne_bf16(x - bf16_f32(h));
}

// ---------------------------------------------------------------------------
// Prologue: weight slabs (bf16, transposed [col][k]) + A bf16 + all Ax0[t]
// ---------------------------------------------------------------------------
struct PPC {
    const float *x2d, *mask, *A, *Wh0, *Wx1, *Wh1;
    float* Ax0All;
    ushort *Abf, *WzrT0, *WcT0, *WxzrT1, *WhzrT1, *WxcT1, *WhcT1;
};

__global__ __launch_bounds__(256) void prolog_kernel(PPC c) {
    __shared__ float sh[4096];
    const int bid = blockIdx.x, tid = threadIdx.x;
    if (bid < 2048) {
        // x-job: Ax0All[t] = A @ (x_t * mask_t), exact fp32
        int t = bid >> 5, lb = bid & 31;
        int b = lb >> 2, rt = lb & 3;
        float* xs = sh;          // [256][8]
        float* red = sh + 2048;  // [64][4][8]
        float* Ax0 = c.Ax0All + (size_t)t * 16384;
        const float* xbase = c.x2d + ((size_t)(b * TT + t) * 256) * 6;
        const float* mbase = c.mask + (size_t)(b * TT + t) * 256;
        {
            int m = tid;
            float mk = mbase[m];
            #pragma unroll
            for (int d = 0; d < 6; ++d) xs[m * 8 + d] = xbase[m * 6 + d] * mk;
        }
        __syncthreads();
        int i = tid & 63, q = tid >> 6;
        const float* arow = c.A + (size_t)(rt * 64 + i) * 256 + q * 64;
        float a6[6] = {0.f, 0.f, 0.f, 0.f, 0.f, 0.f};
        for (int m = 0; m < 64; ++m) {
            float a = arow[m];
            const float* xv = &xs[(q * 64 + m) * 8];
            #pragma unroll
            for (int d = 0; d < 6; ++d) a6[d] = fmaf(a, xv[d], a6[d]);
        }
        #pragma unroll
        for (int d = 0; d < 6; ++d) red[(i * 4 + q) * 8 + d] = a6[d];
        __syncthreads();
        for (int idx2 = tid; idx2 < 64 * 6; idx2 += 256) {
            int ii = idx2 / 6, d = idx2 - ii * 6;
            float s = red[(ii * 4 + 0) * 8 + d] + red[(ii * 4 + 1) * 8 + d]
                    + red[(ii * 4 + 2) * 8 + d] + red[(ii * 4 + 3) * 8 + d];
            Ax0[(size_t)(b * 256 + rt * 64 + ii) * 8 + d] = s;
        }
    } else {
        int idx = (bid - 2048) * 256 + tid;
        if (idx >= 655360) return;
        if (idx < 65536) { c.Abf[idx] = rne_bf16(c.A[idx]); return; }
        int e = idx - 65536;
        ushort* dst; const float* src; int colOff;
        if      (e < 131072) { dst = c.WzrT0;  src = c.Wh0; colOff = 0;   }
        else if (e < 196608) { dst = c.WcT0;   src = c.Wh0; colOff = 512; e -= 131072; }
        else if (e < 327680) { dst = c.WxzrT1; src = c.Wx1; colOff = 0;   e -= 196608; }
        else if (e < 458752) { dst = c.WhzrT1; src = c.Wh1; colOff = 0;   e -= 327680; }
        else if (e < 524288) { dst = c.WxcT1;  src = c.Wx1; colOff = 512; e -= 458752; }
        else                 { dst = c.WhcT1;  src = c.Wh1; colOff = 512; e -= 524288; }
        int col = e >> 8, k = e & 255;
        dst[e] = rne_bf16(src[k * 768 + colOff + col]);
    }
}

// ---------------------------------------------------------------------------
// V1: panel A-apply.  P[p*64 .. +64][0:256] = A(panel) @ X, X via XT split.
// Output split-stored row-major to Phi/Plo.
// ---------------------------------------------------------------------------
__device__ void v1_aapply(int p, int tid, ushort* lds, const ushort* Abf,
    const ushort* XThi, const ushort* XTlo, ushort* Phi, ushort* Plo)
{
    ushort* As  = lds;                  // [64][LV1]
    ushort* Bhi = lds + 64 * LV1;       // [256][LV1]
    ushort* Blo = Bhi + 256 * LV1;
    const int b = p >> 2, rt = p & 3;
    const int lane = tid & 63, wave = tid >> 6;
    const int wr = wave >> 1, wc = wave & 1;
    const int l15 = lane & 15, q8 = (lane >> 4) << 3, quad = lane >> 4;

    f32x4 acc[4][2][2];
    #pragma unroll
    for (int ct = 0; ct < 4; ++ct)
        #pragma unroll
        for (int i = 0; i < 2; ++i)
            #pragma unroll
            for (int j = 0; j < 2; ++j) acc[ct][i][j] = 0.f;

    const ushort* Arow = Abf + (size_t)(rt * 64 + (tid >> 2)) * 256 + ((tid & 3) << 3);
    const ushort* Xh = XThi + (size_t)(b * 256 + tid) * 256;
    const ushort* Xl = XTlo + (size_t)(b * 256 + tid) * 256;
    ushort* wA = &As[(tid >> 2) * LV1 + ((tid & 3) << 3)];
    ushort* wH = &Bhi[tid * LV1];
    ushort* wL = &Blo[tid * LV1];

    for (int k0 = 0; k0 < 256; k0 += 32) {
        __syncthreads();
        *(uint4*)wA = *(const uint4*)(Arow + k0);
        #pragma unroll
        for (int q = 0; q < 4; ++q) *(uint4*)(wH + q * 8) = *(const uint4*)(Xh + k0 + q * 8);
        #pragma unroll
        for (int q = 0; q < 4; ++q) *(uint4*)(wL + q * 8) = *(const uint4*)(Xl + k0 + q * 8);
        __syncthreads();
        s16x8 af[2];
        #pragma unroll
        for (int i = 0; i < 2; ++i)
            af[i] = *(const s16x8*)&As[(wr * 32 + i * 16 + l15) * LV1 + q8];
        #pragma unroll
        for (int ct = 0; ct < 4; ++ct)
            #pragma unroll
            for (int j = 0; j < 2; ++j) {
                const int col = ct * 64 + wc * 32 + j * 16 + l15;
                s16x8 bh = *(const s16x8*)&Bhi[col * LV1 + q8];
                s16x8 bl = *(const s16x8*)&Blo[col * LV1 + q8];
                #pragma unroll
                for (int i = 0; i < 2; ++i) {
                    acc[ct][i][j] = MFMA(af[i], bh, acc[ct][i][j]);
                    acc[ct][i][j] = MFMA(af[i], bl, acc[ct][i][j]);
                }
            }
    }
    #pragma unroll
    for (int ct = 0; ct < 4; ++ct)
        #pragma unroll
        for (int i = 0; i < 2; ++i)
            #pragma unroll
            for (int j = 0; j < 2; ++j) {
                const int col = ct * 64 + wc * 32 + j * 16 + l15;
                const int row0 = p * 64 + wr * 32 + i * 16 + quad * 4;
                #pragma unroll
                for (int r = 0; r < 4; ++r) {
                    ushort hi, lo;
                    split2(acc[ct][i][j][r], hi, lo);
                    Phi[(size_t)(row0 + r) * 256 + col] = hi;
                    Plo[(size_t)(row0 + r) * 256 + col] = lo;
                }
            }
}

// ---------------------------------------------------------------------------
// V2: panel gate GEMM.  acc += sum_g  L_g(split, row-major) @ R_g([col][k])
// ---------------------------------------------------------------------------
__device__ void v2_wapply(int p, int tid, ushort* lds, int ngemm,
    const ushort* L0hi, const ushort* L0lo, const ushort* R0,
    const ushort* L1hi, const ushort* L1lo, const ushort* R1,
    f32x4 (&acc)[4][2][2])
{
    ushort* Lh = lds;                   // [64][LV2]
    ushort* Ll = lds + 64 * LV2;
    ushort* Bs = lds + 2 * 64 * LV2;    // [256][LV2]
    const int lane = tid & 63, wave = tid >> 6;
    const int wr = wave >> 1, wc = wave & 1;
    const int l15 = lane & 15, q8 = (lane >> 4) << 3;

    const int t2 = tid & 127;
    const int lrow = t2 >> 1, lkh = (t2 & 1) * 32;
    ushort* wLd = ((tid < 128) ? Lh : Ll) + lrow * LV2 + lkh;
    ushort* wBd = &Bs[tid * LV2];

    for (int g = 0; g < ngemm; ++g) {
        const ushort* Lsrc = (g ? (tid < 128 ? L1hi : L1lo)
                                : (tid < 128 ? L0hi : L0lo))
                             + (size_t)(p * 64 + lrow) * 256 + lkh;
        const ushort* Rsrc = (g ? R1 : R0) + (size_t)tid * 256;
        for (int k0 = 0; k0 < 256; k0 += 64) {
            __syncthreads();
            #pragma unroll
            for (int q = 0; q < 4; ++q)
                *(uint4*)(wLd + q * 8) = *(const uint4*)(Lsrc + k0 + q * 8);
            #pragma unroll
            for (int q = 0; q < 8; ++q)
                *(uint4*)(wBd + q * 8) = *(const uint4*)(Rsrc + k0 + q * 8);
            __syncthreads();
            #pragma unroll
            for (int sub = 0; sub < 2; ++sub) {
                const int kb = sub * 32 + q8;
                s16x8 ah[2], al[2];
                #pragma unroll
                for (int i = 0; i < 2; ++i) {
                    ah[i] = *(const s16x8*)&Lh[(wr * 32 + i * 16 + l15) * LV2 + kb];
                    al[i] = *(const s16x8*)&Ll[(wr * 32 + i * 16 + l15) * LV2 + kb];
                }
                #pragma unroll
                for (int ct = 0; ct < 4; ++ct)
                    #pragma unroll
                    for (int j = 0; j < 2; ++j) {
                        s16x8 bf = *(const s16x8*)&Bs[(ct * 64 + wc * 32 + j * 16 + l15) * LV2 + kb];
                        #pragma unroll
                        for (int i = 0; i < 2; ++i) {
                            acc[ct][i][j] = MFMA(ah[i], bf, acc[ct][i][j]);
                            acc[ct][i][j] = MFMA(al[i], bf, acc[ct][i][j]);
                        }
                    }
            }
        }
    }
}

// ---------------------------------------------------------------------------
// Epilogues (index math carried from the round-2-verified kernels)
// ---------------------------------------------------------------------------
__device__ void epi_zr(f32x4 (&acc)[4][2][2], int p, int tid, int gOff,
    const float* bias, int useK6, const float* Ax0t, const float* Wx0,
    const float* h, float* zOut, ushort* Thi, ushort* Tlo, int isZ)
{
    const int lane = tid & 63, wave = tid >> 6;
    const int wr = wave >> 1, wc = wave & 1;
    const int l15 = lane & 15, quad = lane >> 4;
    const int b = p >> 2;
    #pragma unroll
    for (int ct = 0; ct < 4; ++ct) {
        int cg[2]; float bs[2]; float w6[2][6];
        #pragma unroll
        for (int j = 0; j < 2; ++j) {
            cg[j] = ct * 64 + wc * 32 + j * 16 + l15;
            bs[j] = bias[gOff + cg[j]];
            if (useK6)
                #pragma unroll
                for (int d = 0; d < 6; ++d)
                    w6[j][d] = Wx0[d * 768 + gOff + cg[j]];
        }
        #pragma unroll
        for (int i = 0; i < 2; ++i) {
            const int m0 = (p & 3) * 64 + wr * 32 + i * 16 + quad * 4;  // local row in batch
            ushort hi4[2][4], lo4[2][4];
            #pragma unroll
            for (int r = 0; r < 4; ++r) {
                const int row = b * 256 + m0 + r;
                float k6a[6];
                if (useK6) {
                    const float* ax = Ax0t + (size_t)row * 8;
                    #pragma unroll
                    for (int d = 0; d < 6; ++d) k6a[d] = ax[d];
                }
                #pragma unroll
                for (int j = 0; j < 2; ++j) {
                    float v = acc[ct][i][j][r] + bs[j];
                    if (useK6)
                        #pragma unroll
                        for (int d = 0; d < 6; ++d) v = fmaf(k6a[d], w6[j][d], v);
                    float s = 1.f / (1.f + __expf(-v));
                    if (isZ) {
                        zOut[(size_t)row * 256 + cg[j]] = s;
                    } else {
                        float rh = s * h[(size_t)row * 256 + cg[j]];
                        split2(rh, hi4[j][r], lo4[j][r]);
                    }
                }
            }
            if (!isZ)
                #pragma unroll
                for (int j = 0; j < 2; ++j) {
                    size_t off = (size_t)b * 65536 + (size_t)cg[j] * 256 + m0;
                    *(ushort4*)&Thi[off] = make_ushort4(hi4[j][0], hi4[j][1], hi4[j][2], hi4[j][3]);
                    *(ushort4*)&Tlo[off] = make_ushort4(lo4[j][0], lo4[j][1], lo4[j][2], lo4[j][3]);
                }
        }
    }
}

__device__ void epi_c(f32x4 (&acc)[4][2][2], int p, int tid,
    const float* bias, int useK6, const float* Ax0t, const float* Wx0,
    const float* z, float* h, ushort* Thi, ushort* Tlo)
{
    const int lane = tid & 63, wave = tid >> 6;
    const int wr = wave >> 1, wc = wave & 1;
    const int l15 = lane & 15, quad = lane >> 4;
    const int b = p >> 2;
    #pragma unroll
    for (int ct = 0; ct < 4; ++ct) {
        int cg[2]; float bs[2]; float w6[2][6];
        #pragma unroll
        for (int j = 0; j < 2; ++j) {
            cg[j] = ct * 64 + wc * 32 + j * 16 + l15;
            bs[j] = bias[512 + cg[j]];
            if (useK6)
                #pragma unroll
                for (int d = 0; d < 6; ++d)
                    w6[j][d] = Wx0[d * 768 + 512 + cg[j]];
        }
        #pragma unroll
        for (int i = 0; i < 2; ++i) {
            const int m0 = (p & 3) * 64 + wr * 32 + i * 16 + quad * 4;
            ushort hi4[2][4], lo4[2][4];
            #pragma unroll
            for (int r = 0; r < 4; ++r) {
                const int row = b * 256 + m0 + r;
                float k6a[6];
                if (useK6) {
                    const float* ax = Ax0t + (size_t)row * 8;
                    #pragma unroll
                    for (int d = 0; d < 6; ++d) k6a[d] = ax[d];
                }
                #pragma unroll
                for (int j = 0; j < 2; ++j) {
                    float v = acc[ct][i][j][r] + bs[j];
                    if (useK6)
                        #pragma unroll
                        for (int d = 0; d < 6; ++d) v = fmaf(k6a[d], w6[j][d], v);
                    float cc = tanhf(v);
                    size_t gi = (size_t)row * 256 + cg[j];
                    float zz = z[gi], hh = h[gi];
                    float hn = zz * hh + (1.f - zz) * cc;
                    h[gi] = hn;
                    split2(hn, hi4[j][r], lo4[j][r]);
                }
            }
            #pragma unroll
            for (int j = 0; j < 2; ++j) {
                size_t off = (size_t)b * 65536 + (size_t)cg[j] * 256 + m0;
                *(ushort4*)&Thi[off] = make_ushort4(hi4[j][0], hi4[j][1], hi4[j][2], hi4[j][3]);
                *(ushort4*)&Tlo[off] = make_ushort4(lo4[j][0], lo4[j][1], lo4[j][2], lo4[j][3]);
            }
        }
    }
}

// ---------------------------------------------------------------------------
// Phase kernel: grid 32 (one block per 64-row panel), 4 phases per step.
// ---------------------------------------------------------------------------
struct PC {
    float *h0, *h1, *z0, *z1, *out;
    const float *Wx0, *b0, *b1, *Wout, *bout;
    const float* Ax0All;
    const ushort *Abf, *WzrT0, *WcT0, *WxzrT1, *WhzrT1, *WxcT1, *WhcT1;
    ushort *h0Thi, *h0Tlo, *h1Thi, *h1Tlo, *rhThi, *rhTlo;
    ushort *AhPhi, *AhPlo, *Ax1hi, *Ax1lo;
    int phase, t;
};

#define ZACC(a) { _Pragma("unroll") for (int _c=0;_c<4;++_c) _Pragma("unroll") for (int _i=0;_i<2;++_i) _Pragma("unroll") for (int _j=0;_j<2;++_j) a[_c][_i][_j]=0.f; }
#define DRAIN() { asm volatile("s_waitcnt vmcnt(0)" ::: "memory"); __syncthreads(); }

__global__ __launch_bounds__(256) void phase_kernel(PC c) {
    __shared__ ushort lds[27648];
    const int p = blockIdx.x, tid = threadIdx.x;
    const float* Ax0t = c.Ax0All + (size_t)c.t * 16384;
    f32x4 acc[4][2][2];

    if (c.phase == 0) {
        // Ah0 = A@h0 -> panel; then z0 (cols 0:256), rh0T (cols 256:512)
        v1_aapply(p, tid, lds, c.Abf, c.h0Thi, c.h0Tlo, c.AhPhi, c.AhPlo);
        DRAIN();
        ZACC(acc);
        v2_wapply(p, tid, lds, 1, c.AhPhi, c.AhPlo, c.WzrT0, nullptr, nullptr, nullptr, acc);
        epi_zr(acc, p, tid, 0, c.b0, 1, Ax0t, c.Wx0, c.h0, c.z0, nullptr, nullptr, 1);
        ZACC(acc);
        v2_wapply(p, tid, lds, 1, c.AhPhi, c.AhPlo, c.WzrT0 + 256 * 256, nullptr, nullptr, nullptr, acc);
        epi_zr(acc, p, tid, 256, c.b0, 1, Ax0t, c.Wx0, c.h0, nullptr, c.rhThi, c.rhTlo, 0);
    } else if (c.phase == 1) {
        // Arh0 = A@rh0 -> panel; h0 = z0*h0 + (1-z0)*tanh(c)  (+ h0T)
        v1_aapply(p, tid, lds, c.Abf, c.rhThi, c.rhTlo, c.AhPhi, c.AhPlo);
        DRAIN();
        ZACC(acc);
        v2_wapply(p, tid, lds, 1, c.AhPhi, c.AhPlo, c.WcT0, nullptr, nullptr, nullptr, acc);
        epi_c(acc, p, tid, c.b0, 1, Ax0t, c.Wx0, c.z0, c.h0, c.h0Thi, c.h0Tlo);
    } else if (c.phase == 2) {
        // Ax1 = A@h0, Ah1 = A@h1; z1, rh1T
        v1_aapply(p, tid, lds, c.Abf, c.h0Thi, c.h0Tlo, c.Ax1hi, c.Ax1lo);
        v1_aapply(p, tid, lds, c.Abf, c.h1Thi, c.h1Tlo, c.AhPhi, c.AhPlo);
        DRAIN();
        ZACC(acc);
        v2_wapply(p, tid, lds, 2, c.Ax1hi, c.Ax1lo, c.WxzrT1,
                  c.AhPhi, c.AhPlo, c.WhzrT1, acc);
        epi_zr(acc, p, tid, 0, c.b1, 0, Ax0t, c.Wx0, c.h1, c.z1, nullptr, nullptr, 1);
        ZACC(acc);
        v2_wapply(p, tid, lds, 2, c.Ax1hi, c.Ax1lo, c.WxzrT1 + 256 * 256,
                  c.AhPhi, c.AhPlo, c.WhzrT1 + 256 * 256, acc);
        epi_zr(acc, p, tid, 256, c.b1, 0, Ax0t, c.Wx0, c.h1, nullptr, c.rhThi, c.rhTlo, 0);
    } else {
        // Arh1; h1 update (+h1T); fused head for this panel
        v1_aapply(p, tid, lds, c.Abf, c.rhThi, c.rhTlo, c.AhPhi, c.AhPlo);
        DRAIN();
        ZACC(acc);
        v2_wapply(p, tid, lds, 2, c.AhPhi, c.AhPlo, c.WhcT1,
                  c.Ax1hi, c.Ax1lo, c.WxcT1, acc);
        epi_c(acc, p, tid, c.b1, 0, Ax0t, c.Wx0, c.z1, c.h1, c.h1Thi, c.h1Tlo);
        DRAIN();
        for (int g = tid; g < 576; g += 256) {
            int rl = g / 9, o = g - rl * 9;
            int row = p * 64 + rl;
            const float* hr = c.h1 + (size_t)row * 256;
            float s = c.bout[o];
            for (int k = 0; k < 256; k += 4) {
                float4 hv = *(const float4*)(hr + k);
                s = fmaf(hv.x, c.Wout[(k + 0) * 9 + o], s);
                s = fmaf(hv.y, c.Wout[(k + 1) * 9 + o], s);
                s = fmaf(hv.z, c.Wout[(k + 2) * 9 + o], s);
                s = fmaf(hv.w, c.Wout[(k + 3) * 9 + o], s);
            }
            int b = row >> 8, n = row & 255;
            c.out[((size_t)(b * TT + c.t) * 256 + n) * 9 + o] = s;
        }
    }
}

// ---------------------------------------------------------------------------
extern "C" void kernel_launch(void* const* d_in, const int* in_sizes, int n_in,
                              void* d_out, int out_size, void* d_ws, size_t ws_size,
                              hipStream_t stream) {
    const size_t SZ = (size_t)2048 * 256;
    float* ws = (float*)d_ws;

    float* h0 = ws;
    float* h1 = ws + SZ;
    ushort* h0Thi = (ushort*)(ws + 2 * SZ);
    ushort* h0Tlo = h0Thi + SZ;
    ushort* h1Thi = h0Tlo + SZ;
    ushort* h1Tlo = h1Thi + SZ;          // ends at ws + 4*SZ (floats)
    float* z0 = ws + 4 * SZ;
    float* z1 = z0 + SZ;
    float* Ax0All = z1 + SZ;             // 2*SZ floats
    ushort* rhThi = (ushort*)(Ax0All + 2 * SZ);
    ushort* rhTlo = rhThi + SZ;
    ushort* AhPhi = rhTlo + SZ;
    ushort* AhPlo = AhPhi + SZ;
    ushort* Ax1hi = AhPlo + SZ;
    ushort* Ax1lo = Ax1hi + SZ;
    ushort* Abf   = Ax1lo + SZ;          // 65536
    ushort* WzrT0 = Abf + 65536;         // 131072
    ushort* WcT0  = WzrT0 + 131072;      // 65536
    ushort* WxzrT1 = WcT0 + 65536;       // 131072
    ushort* WhzrT1 = WxzrT1 + 131072;    // 131072
    ushort* WxcT1  = WhzrT1 + 131072;    // 65536
    ushort* WhcT1  = WxcT1 + 65536;      // 65536

    // zero h0,h1 (fp32) and h0T/h1T split pairs (bf16 zero = 0)
    hipMemsetAsync(ws, 0, 4 * SZ * sizeof(float), stream);

    PPC pp;
    pp.x2d = (const float*)d_in[0];
    pp.mask = (const float*)d_in[1];
    pp.A = (const float*)d_in[2];
    pp.Wh0 = (const float*)d_in[4];
    pp.Wx1 = (const float*)d_in[6];
    pp.Wh1 = (const float*)d_in[7];
    pp.Ax0All = Ax0All;
    pp.Abf = Abf; pp.WzrT0 = WzrT0; pp.WcT0 = WcT0;
    pp.WxzrT1 = WxzrT1; pp.WhzrT1 = WhzrT1; pp.WxcT1 = WxcT1; pp.WhcT1 = WhcT1;
    prolog_kernel<<<dim3(4608), dim3(256), 0, stream>>>(pp);

    PC c;
    c.h0 = h0; c.h1 = h1; c.z0 = z0; c.z1 = z1; c.out = (float*)d_out;
    c.Wx0 = (const float*)d_in[3];
    c.b0 = (const float*)d_in[5];
    c.b1 = (const float*)d_in[8];
    c.Wout = (const float*)d_in[9];
    c.bout = (const float*)d_in[10];
    c.Ax0All = Ax0All;
    c.Abf = Abf; c.WzrT0 = WzrT0; c.WcT0 = WcT0;
    c.WxzrT1 = WxzrT1; c.WhzrT1 = WhzrT1; c.WxcT1 = WxcT1; c.WhcT1 = WhcT1;
    c.h0Thi = h0Thi; c.h0Tlo = h0Tlo; c.h1Thi = h1Thi; c.h1Tlo = h1Tlo;
    c.rhThi = rhThi; c.rhTlo = rhTlo;
    c.AhPhi = AhPhi; c.AhPlo = AhPlo; c.Ax1hi = Ax1hi; c.Ax1lo = Ax1lo;

    for (int t = 0; t < TT; ++t) {
        c.t = t;
        for (int ph = 0; ph < 4; ++ph) {
            c.phase = ph;
            phase_kernel<<<dim3(32), dim3(256), 0, stream>>>(c);
        }
    }
}